// Round 12
// baseline (1581.466 us; speedup 1.0000x reference)
//
#include <hip/hip_runtime.h>
#include <hip/hip_bf16.h>

#define BATCH 4096
#define KD    512     // E = H = 512 (K dimension of both GEMMs)
#define NG    2048    // 4*H gate columns
#define SEQLEN 128

typedef __attribute__((ext_vector_type(8))) short short8;
typedef __attribute__((ext_vector_type(4))) float floatx4;

// s_getreg encoding: id | (offset<<6) | ((width-1)<<11); HW_REG_XCC_ID = 20
#define HWREG_XCC_ID (20 | (0 << 6) | ((4 - 1) << 11))

// async global->LDS, 16B per lane (emits global_load_lds_dwordx4)
__device__ __forceinline__ void gld16(const void* g, void* l) {
  __builtin_amdgcn_global_load_lds(
      (const __attribute__((address_space(1))) void*)g,
      (__attribute__((address_space(3))) void*)l, 16, 0, 0);
}

__device__ __forceinline__ float fast_sig(float x) {
  return __builtin_amdgcn_rcpf(1.0f + __expf(-x));
}
__device__ __forceinline__ float fast_tanh(float x) {
  return 1.0f - 2.0f * __builtin_amdgcn_rcpf(1.0f + __expf(2.0f * x));
}

__device__ __forceinline__ unsigned pack_bf16(float lo, float hi) {
  unsigned ul = (unsigned)__builtin_bit_cast(unsigned short, __float2bfloat16(lo));
  unsigned uh = (unsigned)__builtin_bit_cast(unsigned short, __float2bfloat16(hi));
  return (uh << 16) | ul;
}
__device__ __forceinline__ float unpack_lo(unsigned u) {
  u <<= 16; return __builtin_bit_cast(float, u);
}
__device__ __forceinline__ float unpack_hi(unsigned u) {
  u &= 0xffff0000u; return __builtin_bit_cast(float, u);
}

// ---- load the 7-subtile weight panel (kt=0..6), r6/r7-PROVEN 0-conflict ----
// LDS layout [7 kt][128 row][8 chunks of 16B] = 112 KB; 128-B rows + 3-bit
// XOR. Chunk cc of [kt][row] holds global k-chunk kt*8 + (cc ^ (row&7)).
__device__ __forceinline__ void load_panel112(const short* __restrict__ W, int bn,
                                              short* __restrict__ lWB, int tid) {
#pragma unroll
  for (int i = 0; i < 14; ++i) {            // 7168 chunks / 512 threads
    int q = i * 512 + tid;
    int kt = q >> 10;                       // 0..6
    int rem = q & 1023;
    int row = rem >> 3, cc = rem & 7;
    int cs = cc ^ (row & 7);                // unswizzle -> global chunk
    gld16(W + (size_t)(bn + row) * KD + (kt * 8 + cs) * 8, lWB + q * 8);
  }
}

// ---- kt=7 B-fragment load: returns ONE short8 (never an array — rule #20;
// r9's array form went to scratch and thrashed L2 with 3.5 MB/step spill) ----
__device__ __forceinline__ short8 ldb7(const short* __restrict__ W, int bn,
                                       int wn, int lane, int h, int j) {
  int brow = wn * 64 + j * 16 + (lane & 15);
  return *(const short8*)
      &W[(size_t)(bn + brow) * KD + (size_t)(56 + h * 4 + (lane >> 4)) * 8];
}

// ---- stage one BK=32 A half-tile (16 KB), r4/r5/r8-PROVEN zero-conflict
// paired-row layout: global row r, k-chunk kc (0..3) -> lr = r>>1,
// c' = (r&1)*4+kc, stored at chunk c'^(lr&7).
__device__ __forceinline__ void stageA32(const short* __restrict__ A, int bm,
                                         int p, short* __restrict__ dst, int tid) {
  const int k0 = p * 32;
#pragma unroll
  for (int i = 0; i < 2; ++i) {             // 1024 chunks / 512 threads
    int q = i * 512 + tid;
    int lr = q >> 3, c1 = q & 7;
    int c0 = c1 ^ (lr & 7);                 // unswizzle to find source
    int row = lr * 2 + (c0 >> 2);
    int kc = c0 & 3;
    gld16(A + (size_t)(bm + row) * KD + k0 + kc * 8, dst + q * 8);
  }
}

// ---- GEMM: r12 = r9's 2-deep pipeline with NAMED b7 registers ----
// 3 A-buffers, counted-vmcnt barriers: per phase issue stage(p+2) ->
// compute(p) -> s_waitcnt vmcnt(2) lgkmcnt(0) [stage(p+1) done, stage(p+2)
// stays IN FLIGHT across the barrier] -> sched_barrier(0) (rule #18) ->
// raw s_barrier. Phases 14,15 take B from the 8 named regs (kt=7).
// k ascending by 32 — bitwise-identical accumulation to r7/r8.
__device__ __forceinline__ void gemm_pipe(
    const short* __restrict__ A, const short* __restrict__ lWB,
    short* __restrict__ lAb,
    short8 b7a0, short8 b7a1, short8 b7a2, short8 b7a3,
    short8 b7b0, short8 b7b1, short8 b7b2, short8 b7b3,
    floatx4 acc[4][4], int bm, int lane, int wm, int wn, int tid) {
  stageA32(A, bm, 0, lAb, tid);
  stageA32(A, bm, 1, lAb + 8192, tid);
  asm volatile("s_waitcnt vmcnt(2)" ::: "memory");   // stage(0) done
  __builtin_amdgcn_sched_barrier(0);
  __builtin_amdgcn_s_barrier();
#pragma unroll
  for (int p = 0; p < 16; ++p) {
    if (p < 14) stageA32(A, bm, p + 2, lAb + ((p + 2) % 3) * 8192, tid);
    const short* lA = lAb + (p % 3) * 8192;
    short8 a[4], b[4];
    const int kb = (p & 1) * 4 + (lane >> 4);
    if (p < 14) {
      const int kt = p >> 1;
#pragma unroll
      for (int j = 0; j < 4; ++j) {
        int brow = wn * 64 + j * 16 + (lane & 15);      // 0..127
        int cc = kb ^ (brow & 7);
        b[j] = *(const short8*)&lWB[kt * 8192 + brow * 64 + cc * 8];
      }
    } else if (p == 14) {
      b[0] = b7a0; b[1] = b7a1; b[2] = b7a2; b[3] = b7a3;   // literal select
    } else {
      b[0] = b7b0; b[1] = b7b1; b[2] = b7b2; b[3] = b7b3;
    }
#pragma unroll
    for (int mi = 0; mi < 4; ++mi) {
      int arow = wm * 64 + mi * 16 + (lane & 15);       // 0..255
      int lr = arow >> 1;
      int cc = (((arow & 1) << 2) + (lane >> 4)) ^ (lr & 7);
      a[mi] = *(const short8*)&lA[lr * 64 + cc * 8];
    }
#pragma unroll
    for (int mi = 0; mi < 4; ++mi)
#pragma unroll
      for (int j = 0; j < 4; ++j)
        acc[mi][j] =
            __builtin_amdgcn_mfma_f32_16x16x32_bf16(a[mi], b[j], acc[mi][j], 0, 0, 0);
    if (p < 15) {
      if (p == 14)
        asm volatile("s_waitcnt vmcnt(0) lgkmcnt(0)" ::: "memory");  // last stage
      else
        asm volatile("s_waitcnt vmcnt(2) lgkmcnt(0)" ::: "memory");  // counted
      __builtin_amdgcn_sched_barrier(0);
      __builtin_amdgcn_s_barrier();
    }
  }
  __syncthreads();   // full drain: all reads done before any buffer reuse
}

// ---- GEMM core for the FALLBACK kernels (round-1 proven, unchanged) ----
template <int TBM, int TBN, int NT>
__device__ __forceinline__ void gemm_tile(const short* __restrict__ A,
                                          const short* __restrict__ Bw,
                                          floatx4 acc[4][4],
                                          short* lA, short* lB,
                                          int bm, int bn,
                                          int lane, int wm, int wn, int tid) {
#pragma unroll 1
  for (int kt = 0; kt < KD / 64; ++kt) {
    const int k0 = kt * 64;
#pragma unroll
    for (int i = 0; i < TBM * 8 / NT; ++i) {
      int q = i * NT + tid;
      int row = q >> 3, cs = q & 7;
      int cc = cs ^ (row & 7);
      gld16(A + (size_t)(bm + row) * KD + k0 + cc * 8, lA + q * 8);
    }
#pragma unroll
    for (int i = 0; i < TBN * 8 / NT; ++i) {
      int q = i * NT + tid;
      int row = q >> 3, cs = q & 7;
      int cc = cs ^ (row & 7);
      gld16(Bw + (size_t)(bn + row) * KD + k0 + cc * 8, lB + q * 8);
    }
    __syncthreads();
#pragma unroll
    for (int ks = 0; ks < 2; ++ks) {
      short8 a[4], b[4];
#pragma unroll
      for (int mi = 0; mi < 4; ++mi) {
        int arow = wm * 64 + mi * 16 + (lane & 15);
        int ch = (ks * 4 + (lane >> 4)) ^ (arow & 7);
        a[mi] = *(const short8*)&lA[arow * 64 + ch * 8];
      }
#pragma unroll
      for (int j = 0; j < 4; ++j) {
        int brow = wn * 64 + j * 16 + (lane & 15);
        int ch = (ks * 4 + (lane >> 4)) ^ (brow & 7);
        b[j] = *(const short8*)&lB[brow * 64 + ch * 8];
      }
#pragma unroll
      for (int mi = 0; mi < 4; ++mi)
#pragma unroll
        for (int j = 0; j < 4; ++j)
          acc[mi][j] =
              __builtin_amdgcn_mfma_f32_16x16x32_bf16(a[mi], b[j], acc[mi][j], 0, 0, 0);
    }
    __syncthreads();
  }
}

// ---- intra-XCD group barrier (r5-proven, bounded spin) ----
__device__ __forceinline__ void group_barrier_xcd(unsigned* cnt, unsigned target) {
  __syncthreads();   // all threads' h-stores drained to L2 (vmcnt(0) in lowering)
  if (threadIdx.x == 0) {
    __hip_atomic_fetch_add(cnt, 1u, __ATOMIC_RELAXED, __HIP_MEMORY_SCOPE_AGENT);
    unsigned guard = 0;
    while (__hip_atomic_load(cnt, __ATOMIC_RELAXED, __HIP_MEMORY_SCOPE_AGENT) <
               target &&
           ++guard < (1u << 20)) {
      __builtin_amdgcn_s_sleep(1);
    }
    asm volatile("buffer_inv sc0" ::: "memory");     // L1-only invalidate
    asm volatile("s_waitcnt vmcnt(0)" ::: "memory"); // inv complete
  }
  __syncthreads();
}

// =====================================================================
// Persistent cooperative kernel — r12: r9's 2-deep counted-vmcnt pipeline
// with the diagnosed spill FIXED (named b7 regs, no array — rule #20).
// 256 blocks x 512 threads, 1 block/CU. LDS = 160 KiB exactly:
// panel [7][128][64] 112 KB + 3 x 16 KB A buffers (BK=32, paired-row).
// kt=7 B-frags in 8 named short8 (32 VGPRs). Counted vmcnt(2) barriers
// keep one stage permanently in flight — removes r8's per-phase drain.
// Block tile 256(batch) x 128(gates); wave 64x64 (wm 0..3, wn 0..1).
// Groups: 16 blocks sharing bm (2 groups/XCD), verified via XCC_ID.
// =====================================================================
__global__ __launch_bounds__(512, 1) void lstm_persist(
    const short* __restrict__ xbf,    // bf16 [4096][512]
    const short* __restrict__ wih,    // bf16 [2048][512] permuted rows
    const short* __restrict__ whh,    // bf16 [2048][512] permuted rows
    const float* __restrict__ biasp,  // fp32 [2048] permuted
    const float* __restrict__ c0,     // fp32 [4096][512]
    short* __restrict__ hA, short* __restrict__ hB,
    float* __restrict__ outH, float* __restrict__ outC,
    unsigned* __restrict__ sync_area) {  // [0,8): per-XCD reg cnt; +256: group cnts
  extern __shared__ __align__(16) char dsm[];
  short* lWB = (short*)dsm;                 // 112 KB weight panel (kt 0..6)
  short* lAb = (short*)(dsm + 114688);      // 3 x 16 KB A buffers

  const int tid = threadIdx.x;
  const int lane = tid & 63;
  const int wid = tid >> 6;          // 0..7
  const int wm = wid >> 1;           // 0..3  (64-row slice of the 256)
  const int wn = wid & 1;            // 0..1  (64-col slice of the 128)

  // ---- dynamic tile assignment from PHYSICAL XCD id (broadcast via lAb) ----
  if (tid == 0) {
    int px = __builtin_amdgcn_s_getreg(HWREG_XCC_ID) & 7;
    unsigned r = __hip_atomic_fetch_add(&sync_area[px], 1u, __ATOMIC_RELAXED,
                                        __HIP_MEMORY_SCOPE_AGENT);
    // exactly 32 blocks/XCD (1 block/CU via LDS + cooperative co-residency)
    ((int*)lAb)[0] = px * 2 + (int)((r >> 4) & 1);  // group id 0..15
    ((int*)lAb)[1] = (int)(r & 15);                 // member 0..15
  }
  __syncthreads();
  const int gid = ((int*)lAb)[0];
  const int by  = ((int*)lAb)[1];
  __syncthreads();                           // reads done before lAb reuse
  const int bm = gid * 256;
  const int bn = by * 128;
  unsigned* gcnt = sync_area + 256 + gid * 32;  // 128B line per group

  const int houter = by * 2 + wn;            // 0..31
  const int hcol = houter * 16 + (lane & 15);
  const int rb = houter * 64 + (lane & 15);

  // ---- phase 0: x_proj with wih (panel112 + named b7 regs) ----
  load_panel112(wih, bn, lWB, tid);
  short8 b7a0 = ldb7(wih, bn, wn, lane, 0, 0), b7a1 = ldb7(wih, bn, wn, lane, 0, 1),
         b7a2 = ldb7(wih, bn, wn, lane, 0, 2), b7a3 = ldb7(wih, bn, wn, lane, 0, 3),
         b7b0 = ldb7(wih, bn, wn, lane, 1, 0), b7b1 = ldb7(wih, bn, wn, lane, 1, 1),
         b7b2 = ldb7(wih, bn, wn, lane, 1, 2), b7b3 = ldb7(wih, bn, wn, lane, 1, 3);
  __syncthreads();                           // panel loaded (vmcnt drained)
  floatx4 acc[4][4] = {};
  gemm_pipe(xbf, lWB, lAb, b7a0, b7a1, b7a2, b7a3, b7b0, b7b1, b7b2, b7b3,
            acc, bm, lane, wm, wn, tid);

  const float b0 = biasp[rb], b1 = biasp[rb + 16], b2 = biasp[rb + 32],
              b3 = biasp[rb + 48];
  unsigned xprP[4][4][2];  // [mi][reg][pair] : (i,f) and (g,o) — 32 VGPRs
  float creg[4][4];        // 16 VGPRs
#pragma unroll
  for (int mi = 0; mi < 4; ++mi) {
    const int mrow0 = bm + wm * 64 + mi * 16 + (lane >> 4) * 4;
#pragma unroll
    for (int reg = 0; reg < 4; ++reg) {
      xprP[mi][reg][0] = pack_bf16(acc[mi][0][reg] + b0, acc[mi][1][reg] + b1);
      xprP[mi][reg][1] = pack_bf16(acc[mi][2][reg] + b2, acc[mi][3][reg] + b3);
      creg[mi][reg] = c0[(size_t)(mrow0 + reg) * KD + hcol];
    }
  }

  // ---- swap in the recurrent weights (one-time) ----
  b7a0 = ldb7(whh, bn, wn, lane, 0, 0); b7a1 = ldb7(whh, bn, wn, lane, 0, 1);
  b7a2 = ldb7(whh, bn, wn, lane, 0, 2); b7a3 = ldb7(whh, bn, wn, lane, 0, 3);
  b7b0 = ldb7(whh, bn, wn, lane, 1, 0); b7b1 = ldb7(whh, bn, wn, lane, 1, 1);
  b7b2 = ldb7(whh, bn, wn, lane, 1, 2); b7b3 = ldb7(whh, bn, wn, lane, 1, 3);
  load_panel112(whh, bn, lWB, tid);  // safe: gemm_pipe ended with syncthreads
  __syncthreads();                   // whh resident from here on

  // ---- 128 recurrent steps ----
#pragma unroll 1
  for (int t = 0; t < SEQLEN; ++t) {
    const short* hin = (t & 1) ? hB : hA;
    short* hout = (t & 1) ? hA : hB;

#pragma unroll
    for (int mi = 0; mi < 4; ++mi)
#pragma unroll
      for (int j = 0; j < 4; ++j)
        acc[mi][j] = floatx4{0.f, 0.f, 0.f, 0.f};

    gemm_pipe(hin, lWB, lAb, b7a0, b7a1, b7a2, b7a3, b7b0, b7b1, b7b2, b7b3,
              acc, bm, lane, wm, wn, tid);

#pragma unroll
    for (int mi = 0; mi < 4; ++mi) {
      const int mrow0 = bm + wm * 64 + mi * 16 + (lane >> 4) * 4;
#pragma unroll
      for (int reg = 0; reg < 4; ++reg) {
        const int m = mrow0 + reg;
        float gi = acc[mi][0][reg] + unpack_lo(xprP[mi][reg][0]);
        float gf = acc[mi][1][reg] + unpack_hi(xprP[mi][reg][0]);
        float gg = acc[mi][2][reg] + unpack_lo(xprP[mi][reg][1]);
        float go = acc[mi][3][reg] + unpack_hi(xprP[mi][reg][1]);
        float si = fast_sig(gi);
        float sf = fast_sig(gf);
        float tg = fast_tanh(gg);
        float so = fast_sig(go);
        float cn = sf * creg[mi][reg] + si * tg;
        creg[mi][reg] = cn;
        float hn = so * fast_tanh(cn);
        const size_t ci = (size_t)m * KD + hcol;
        ((__hip_bfloat16*)hout)[ci] = __float2bfloat16(hn);
        if (t == SEQLEN - 1) {
          outH[ci] = hn;
          outC[ci] = cn;
        }
      }
    }
    if (t != SEQLEN - 1) group_barrier_xcd(gcnt, 16u * (unsigned)(t + 1));
  }
}

// =====================================================================
// Fallback path (round-1 proven, 2848 us): per-step kernels
// =====================================================================
__global__ __launch_bounds__(256, 2) void lstm_step(
    const short* __restrict__ hin, __hip_bfloat16* __restrict__ hout_bf,
    const short* __restrict__ W, const float* __restrict__ xp,
    float* __restrict__ c, float* __restrict__ hout_f32) {
  __shared__ __align__(16) short lA[128 * 64];
  __shared__ __align__(16) short lB[128 * 64];
  const int tid = threadIdx.x;
  const int lane = tid & 63;
  const int wid = tid >> 6;
  const int wm = wid >> 1, wn = wid & 1;
  const int bm = blockIdx.x * 128, bn = blockIdx.y * 128;

  floatx4 acc[4][4] = {};
  gemm_tile<128, 128, 256>(hin, W, acc, lA, lB, bm, bn, lane, wm, wn, tid);

  const int houter = blockIdx.y * 2 + wn;
  const int hcol = houter * 16 + (lane & 15);
  const int rb = houter * 64 + (lane & 15);
#pragma unroll
  for (int mi = 0; mi < 4; ++mi) {
    const int mrow0 = bm + wm * 64 + mi * 16 + (lane >> 4) * 4;
#pragma unroll
    for (int reg = 0; reg < 4; ++reg) {
      const int m = mrow0 + reg;
      const float* xpr = xp + (size_t)m * NG + rb;
      float si = fast_sig(acc[mi][0][reg] + xpr[0]);
      float sf = fast_sig(acc[mi][1][reg] + xpr[16]);
      float tg = fast_tanh(acc[mi][2][reg] + xpr[32]);
      float so = fast_sig(acc[mi][3][reg] + xpr[48]);
      const int ci = m * KD + hcol;
      float cn = sf * c[ci] + si * tg;
      c[ci] = cn;
      float hn = so * fast_tanh(cn);
      hout_bf[ci] = __float2bfloat16(hn);
      if (hout_f32) hout_f32[ci] = hn;
    }
  }
}

__global__ __launch_bounds__(256, 2) void xproj_gemm(
    const short* __restrict__ xbf, const short* __restrict__ Wih,
    const float* __restrict__ biasp, float* __restrict__ xp) {
  __shared__ __align__(16) short lA[128 * 64];
  __shared__ __align__(16) short lB[128 * 64];
  const int tid = threadIdx.x;
  const int lane = tid & 63;
  const int wid = tid >> 6;
  const int wm = wid >> 1, wn = wid & 1;
  const int bm = blockIdx.x * 128, bn = blockIdx.y * 128;

  floatx4 acc[4][4] = {};
  gemm_tile<128, 128, 256>(xbf, Wih, acc, lA, lB, bm, bn, lane, wm, wn, tid);

  const int houter = blockIdx.y * 2 + wn;
  const int rb = houter * 64 + (lane & 15);
  const float b0 = biasp[rb], b1 = biasp[rb + 16], b2 = biasp[rb + 32],
              b3 = biasp[rb + 48];
#pragma unroll
  for (int mi = 0; mi < 4; ++mi) {
    const int mrow0 = bm + wm * 64 + mi * 16 + (lane >> 4) * 4;
#pragma unroll
    for (int reg = 0; reg < 4; ++reg) {
      float* xpr = xp + (size_t)(mrow0 + reg) * NG + rb;
      xpr[0]  = acc[mi][0][reg] + b0;
      xpr[16] = acc[mi][1][reg] + b1;
      xpr[32] = acc[mi][2][reg] + b2;
      xpr[48] = acc[mi][3][reg] + b3;
    }
  }
}

// ---- prep kernels ----
__global__ void permw_k(const float* __restrict__ w,
                        __hip_bfloat16* __restrict__ o) {
  int idx = blockIdx.x * 256 + threadIdx.x;  // 2048*512
  int r = idx >> 9, k = idx & 511;
  int hout = r >> 6, g = (r >> 4) & 3, hin = r & 15;
  o[idx] = __float2bfloat16(w[(size_t)((g << 9) + hout * 16 + hin) * 512 + k]);
}

__global__ void bias_k(const float* __restrict__ bi, const float* __restrict__ bh,
                       float* __restrict__ o) {
  int r = blockIdx.x * 256 + threadIdx.x;  // 2048
  int hout = r >> 6, g = (r >> 4) & 3, hin = r & 15;
  int n = (g << 9) + hout * 16 + hin;
  o[r] = bi[n] + bh[n];
}

__global__ void f2bf_k(const float* __restrict__ in,
                       __hip_bfloat16* __restrict__ out, int n) {
  int i = blockIdx.x * 256 + threadIdx.x;
  if (i < n) out[i] = __float2bfloat16(in[i]);
}

extern "C" void kernel_launch(void* const* d_in, const int* in_sizes, int n_in,
                              void* d_out, int out_size, void* d_ws, size_t ws_size,
                              hipStream_t stream) {
  const float* start_emb = (const float*)d_in[0];
  const float* h0 = (const float*)d_in[1];
  const float* c0 = (const float*)d_in[2];
  const float* w_ih = (const float*)d_in[3];
  const float* w_hh = (const float*)d_in[4];
  const float* b_ih = (const float*)d_in[5];
  const float* b_hh = (const float*)d_in[6];
  // seq_length (d_in[7]) fixed at 128 by the reference setup.

  char* ws = (char*)d_ws;
  __hip_bfloat16* whh_p = (__hip_bfloat16*)(ws);                // 2 MB
  __hip_bfloat16* wih_p = (__hip_bfloat16*)(ws + (2ll << 20));  // 2 MB
  __hip_bfloat16* xbf   = (__hip_bfloat16*)(ws + (4ll << 20));  // 4 MB
  __hip_bfloat16* hbufA = (__hip_bfloat16*)(ws + (8ll << 20));  // 4 MB
  __hip_bfloat16* hbufB = (__hip_bfloat16*)(ws + (12ll << 20)); // 4 MB
  float* biasp          = (float*)(ws + (16ll << 20));          // 8 KB
  unsigned* sync_area   = (unsigned*)(ws + (16ll << 20) + 65536); // 8 KB
  float* xp             = (float*)(ws + (17ll << 20));          // 32 MB (fallback)

  float* outH = (float*)d_out;
  float* outC = (float*)d_out + (size_t)BATCH * KD;

  permw_k<<<4096, 256, 0, stream>>>(w_hh, whh_p);
  permw_k<<<4096, 256, 0, stream>>>(w_ih, wih_p);
  bias_k<<<8, 256, 0, stream>>>(b_ih, b_hh, biasp);
  f2bf_k<<<8192, 256, 0, stream>>>(start_emb, xbf, BATCH * KD);
  f2bf_k<<<8192, 256, 0, stream>>>(h0, hbufA, BATCH * KD);
  (void)hipMemsetAsync(sync_area, 0, 8192, stream);

  const short* a_xbf = (const short*)xbf;
  const short* a_wih = (const short*)wih_p;
  const short* a_whh = (const short*)whh_p;
  const float* a_bias = biasp;
  const float* a_c0 = c0;
  short* a_hA = (short*)hbufA;
  short* a_hB = (short*)hbufB;
  float* a_outH = outH;
  float* a_outC = outC;
  unsigned* a_sync = sync_area;
  void* args[] = {&a_xbf, &a_wih, &a_whh, &a_bias, &a_c0,
                  &a_hA, &a_hB, &a_outH, &a_outC, &a_sync};
  // 160 KiB dynamic LDS (panel 112K + 3x16K A bufs) => 1 block/CU => 256
  // co-resident blocks = exactly 32 per XCD (G16: verified registration).
  hipError_t e = hipLaunchCooperativeKernel((const void*)lstm_persist,
                                            dim3(256), dim3(512), args,
                                            163840, stream);
  if (e != hipSuccess) {
    // deterministic fallback: proven round-1 per-step path
    (void)hipMemcpyAsync(outC, c0, (size_t)BATCH * KD * sizeof(float),
                         hipMemcpyDeviceToDevice, stream);
    dim3 grid(BATCH / 128, NG / 128);
    xproj_gemm<<<grid, 256, 0, stream>>>((const short*)xbf, (const short*)wih_p,
                                         biasp, xp);
    for (int t = 0; t < SEQLEN; ++t) {
      const short* hin = (const short*)((t & 1) ? hbufB : hbufA);
      __hip_bfloat16* hout = (t & 1) ? hbufA : hbufB;
      lstm_step<<<grid, 256, 0, stream>>>(hin, hout, (const short*)whh_p, xp,
                                          outC, (t == SEQLEN - 1) ? outH : nullptr);
    }
  }
}

// Round 13
// 1442.709 us; speedup vs baseline: 1.0962x; 1.0962x over previous
//
#include <hip/hip_runtime.h>
#include <hip/hip_bf16.h>

#define BATCH 4096
#define KD    512     // E = H = 512 (K dimension of both GEMMs)
#define NG    2048    // 4*H gate columns
#define SEQLEN 128

typedef __attribute__((ext_vector_type(8))) short short8;
typedef __attribute__((ext_vector_type(4))) float floatx4;

// s_getreg encoding: id | (offset<<6) | ((width-1)<<11); HW_REG_XCC_ID = 20
#define HWREG_XCC_ID (20 | (0 << 6) | ((4 - 1) << 11))

// async global->LDS, 16B per lane (emits global_load_lds_dwordx4)
__device__ __forceinline__ void gld16(const void* g, void* l) {
  __builtin_amdgcn_global_load_lds(
      (const __attribute__((address_space(1))) void*)g,
      (__attribute__((address_space(3))) void*)l, 16, 0, 0);
}

__device__ __forceinline__ float fast_sig(float x) {
  return __builtin_amdgcn_rcpf(1.0f + __expf(-x));
}
__device__ __forceinline__ float fast_tanh(float x) {
  return 1.0f - 2.0f * __builtin_amdgcn_rcpf(1.0f + __expf(2.0f * x));
}

__device__ __forceinline__ unsigned pack_bf16(float lo, float hi) {
  unsigned ul = (unsigned)__builtin_bit_cast(unsigned short, __float2bfloat16(lo));
  unsigned uh = (unsigned)__builtin_bit_cast(unsigned short, __float2bfloat16(hi));
  return (uh << 16) | ul;
}
__device__ __forceinline__ float unpack_lo(unsigned u) {
  u <<= 16; return __builtin_bit_cast(float, u);
}
__device__ __forceinline__ float unpack_hi(unsigned u) {
  u &= 0xffff0000u; return __builtin_bit_cast(float, u);
}

// ---- load the 128-row weight panel, repacked per K-tile (r6/r7-PROVEN 0-conflict) ----
// LDS layout [8 kt][128 row][8 chunks of 16B] (16 KB per kt sub-tile, 128 KB
// total). Within a sub-tile: 128-B rows + 3-bit XOR. Chunk cc of [kt][row]
// holds global k-chunk kt*8 + (cc ^ (row&7)).
__device__ __forceinline__ void load_panel128(const short* __restrict__ W, int bn,
                                              short* __restrict__ lWB, int tid) {
#pragma unroll
  for (int i = 0; i < 16; ++i) {            // 8192 chunks / 512 threads
    int q = i * 512 + tid;
    int kt = q >> 10;                       // 1024 chunks per kt sub-tile
    int rem = q & 1023;
    int row = rem >> 3, cc = rem & 7;
    int cs = cc ^ (row & 7);                // unswizzle -> global chunk
    gld16(W + (size_t)(bn + row) * KD + (kt * 8 + cs) * 8, lWB + q * 8);
  }
}

// ---- stage one BK=32 A half-tile (16 KB), r4/r5/r8-PROVEN zero-conflict
// paired-row layout: global row r, k-chunk kc (0..3) -> lr = r>>1,
// c' = (r&1)*4+kc, stored at chunk c'^(lr&7). 128-B lds rows + 3-bit XOR.
__device__ __forceinline__ void stageA32(const short* __restrict__ A, int bm,
                                         int p, short* __restrict__ dst, int tid) {
  const int k0 = p * 32;
#pragma unroll
  for (int i = 0; i < 2; ++i) {             // 1024 chunks / 512 threads
    int q = i * 512 + tid;
    int lr = q >> 3, c1 = q & 7;
    int c0 = c1 ^ (lr & 7);                 // unswizzle to find source
    int row = lr * 2 + (c0 >> 2);
    int kc = c0 & 3;
    gld16(A + (size_t)(bm + row) * KD + k0 + kc * 8, dst + q * 8);
  }
}

// ---- one BK=32 phase of MFMA work (16 MFMA/wave), conflict-free reads ----
__device__ __forceinline__ void compute32(const short* __restrict__ lWB,
                                          const short* __restrict__ lA,
                                          floatx4 acc[4][4], int p,
                                          int lane, int wm, int wn) {
  short8 a[4], b[4];
  const int kt = p >> 1;
  const int kb = (p & 1) * 4 + (lane >> 4);  // chunk within panel sub-tile
#pragma unroll
  for (int j = 0; j < 4; ++j) {              // B first: panel-stable reads
    int brow = wn * 64 + j * 16 + (lane & 15);          // 0..127
    int cc = kb ^ (brow & 7);
    b[j] = *(const short8*)&lWB[kt * 8192 + brow * 64 + cc * 8];
  }
#pragma unroll
  for (int mi = 0; mi < 4; ++mi) {
    int arow = wm * 64 + mi * 16 + (lane & 15);         // 0..255
    int lr = arow >> 1;
    int cc = (((arow & 1) << 2) + (lane >> 4)) ^ (lr & 7);
    a[mi] = *(const short8*)&lA[lr * 64 + cc * 8];
  }
#pragma unroll
  for (int mi = 0; mi < 4; ++mi)
#pragma unroll
    for (int j = 0; j < 4; ++j)
      acc[mi][j] =
          __builtin_amdgcn_mfma_f32_16x16x32_bf16(a[mi], b[j], acc[mi][j], 0, 0, 0);
}

// ---- GEMM: acc += A[bm..bm+256) x panel^T, A DOUBLE-BUFFERED at BK=32 ----
// stage(p+1) issued before compute(p); ONE barrier per phase. The barrier's
// vmcnt(0) drain is covered by ~900 cyc of ds_read+MFMA. k order identical
// to r7 (ascending by 32) => bitwise-same accumulation.
__device__ __forceinline__ void gemm_dbuf(const short* __restrict__ A,
                                          const short* __restrict__ lWB,
                                          short* __restrict__ lAb,
                                          floatx4 acc[4][4],
                                          int bm, int lane, int wm, int wn,
                                          int tid) {
  stageA32(A, bm, 0, lAb, tid);
  __syncthreads();                          // only fully-exposed drain
#pragma unroll 2
  for (int p = 0; p < 16; ++p) {
    if (p < 15) stageA32(A, bm, p + 1, lAb + ((p + 1) & 1) * 8192, tid);
    compute32(lWB, lAb + (p & 1) * 8192, acc, p, lane, wm, wn);
    __syncthreads();                        // stage(p+1) drained; reads done
  }
}

// ---- GEMM core for the FALLBACK kernels (round-1 proven, unchanged) ----
template <int TBM, int TBN, int NT>
__device__ __forceinline__ void gemm_tile(const short* __restrict__ A,
                                          const short* __restrict__ Bw,
                                          floatx4 acc[4][4],
                                          short* lA, short* lB,
                                          int bm, int bn,
                                          int lane, int wm, int wn, int tid) {
#pragma unroll 1
  for (int kt = 0; kt < KD / 64; ++kt) {
    const int k0 = kt * 64;
#pragma unroll
    for (int i = 0; i < TBM * 8 / NT; ++i) {
      int q = i * NT + tid;
      int row = q >> 3, cs = q & 7;
      int cc = cs ^ (row & 7);
      gld16(A + (size_t)(bm + row) * KD + k0 + cc * 8, lA + q * 8);
    }
#pragma unroll
    for (int i = 0; i < TBN * 8 / NT; ++i) {
      int q = i * NT + tid;
      int row = q >> 3, cs = q & 7;
      int cc = cs ^ (row & 7);
      gld16(Bw + (size_t)(bn + row) * KD + k0 + cc * 8, lB + q * 8);
    }
    __syncthreads();
#pragma unroll
    for (int ks = 0; ks < 2; ++ks) {
      short8 a[4], b[4];
#pragma unroll
      for (int mi = 0; mi < 4; ++mi) {
        int arow = wm * 64 + mi * 16 + (lane & 15);
        int ch = (ks * 4 + (lane >> 4)) ^ (arow & 7);
        a[mi] = *(const short8*)&lA[arow * 64 + ch * 8];
      }
#pragma unroll
      for (int j = 0; j < 4; ++j) {
        int brow = wn * 64 + j * 16 + (lane & 15);
        int ch = (ks * 4 + (lane >> 4)) ^ (brow & 7);
        b[j] = *(const short8*)&lB[brow * 64 + ch * 8];
      }
#pragma unroll
      for (int mi = 0; mi < 4; ++mi)
#pragma unroll
        for (int j = 0; j < 4; ++j)
          acc[mi][j] =
              __builtin_amdgcn_mfma_f32_16x16x32_bf16(a[mi], b[j], acc[mi][j], 0, 0, 0);
    }
    __syncthreads();
  }
}

// ---- intra-XCD group barrier (r5-proven, bounded spin) ----
__device__ __forceinline__ void group_barrier_xcd(unsigned* cnt, unsigned target) {
  __syncthreads();   // all threads' h-stores drained to L2 (vmcnt(0) in lowering)
  if (threadIdx.x == 0) {
    __hip_atomic_fetch_add(cnt, 1u, __ATOMIC_RELAXED, __HIP_MEMORY_SCOPE_AGENT);
    unsigned guard = 0;
    while (__hip_atomic_load(cnt, __ATOMIC_RELAXED, __HIP_MEMORY_SCOPE_AGENT) <
               target &&
           ++guard < (1u << 20)) {
      __builtin_amdgcn_s_sleep(1);
    }
    asm volatile("buffer_inv sc0" ::: "memory");     // L1-only invalidate
    asm volatile("s_waitcnt vmcnt(0)" ::: "memory"); // inv complete
  }
  __syncthreads();
}

// =====================================================================
// FINAL (r13 = r8, the session champion at 1448 us).
// Persistent cooperative kernel: 256 blocks x 512 threads, 1 block/CU.
// LDS = 160 KiB exactly: panel [8][128][64] 128 KB + 2 x 16 KB A dbuf.
// Per BK=32 phase: issue stage(p+1) -> compute(p) -> ONE barrier.
// Why this is the stopping point (measured, not assumed):
//  - LDS-read pipe ~12.3k cyc/step/CU is the structural floor at the
//    64x64 wave tile; bigger tiles need >128 acc regs.
//  - The allocator pins this kernel at 128 arch-VGPRs: r6/r9/r12 all
//    spilled (identical +3.5 MB/step scratch-WRITE signature) when any
//    persistent weight registers were added — deeper counted-vmcnt
//    pipelines are register-blocked.
//  - Sync cost bounded <=1 us/step by r10/r11 (two correct alternative
//    flag schemes, neither faster than the r5 group barrier).
//  - Bank conflicts 0, FETCH 37 MB (L2-resident), HBM 0.7% of peak.
// Groups: 16 blocks sharing bm (2 groups/XCD), verified via XCC_ID.
// =====================================================================
__global__ __launch_bounds__(512, 1) void lstm_persist(
    const short* __restrict__ xbf,    // bf16 [4096][512]
    const short* __restrict__ wih,    // bf16 [2048][512] permuted rows
    const short* __restrict__ whh,    // bf16 [2048][512] permuted rows
    const float* __restrict__ biasp,  // fp32 [2048] permuted
    const float* __restrict__ c0,     // fp32 [4096][512]
    short* __restrict__ hA, short* __restrict__ hB,
    float* __restrict__ outH, float* __restrict__ outC,
    unsigned* __restrict__ sync_area) {  // [0,8): per-XCD reg cnt; +256: group cnts
  extern __shared__ __align__(16) char dsm[];
  short* lWB = (short*)dsm;                 // 128 KB persistent weight panel
  short* lAb = (short*)(dsm + 131072);      // 2 x 16 KB A half-tiles (dbuf)

  const int tid = threadIdx.x;
  const int lane = tid & 63;
  const int wid = tid >> 6;          // 0..7
  const int wm = wid >> 1;           // 0..3  (64-row slice of the 256)
  const int wn = wid & 1;            // 0..1  (64-col slice of the 128)

  // ---- dynamic tile assignment from PHYSICAL XCD id (broadcast via lAb) ----
  if (tid == 0) {
    int px = __builtin_amdgcn_s_getreg(HWREG_XCC_ID) & 7;
    unsigned r = __hip_atomic_fetch_add(&sync_area[px], 1u, __ATOMIC_RELAXED,
                                        __HIP_MEMORY_SCOPE_AGENT);
    // exactly 32 blocks/XCD (1 block/CU via LDS + cooperative co-residency)
    ((int*)lAb)[0] = px * 2 + (int)((r >> 4) & 1);  // group id 0..15
    ((int*)lAb)[1] = (int)(r & 15);                 // member 0..15
  }
  __syncthreads();
  const int gid = ((int*)lAb)[0];
  const int by  = ((int*)lAb)[1];
  __syncthreads();                           // reads done before lAb reuse
  const int bm = gid * 256;
  const int bn = by * 128;
  unsigned* gcnt = sync_area + 256 + gid * 32;  // 128B line per group

  const int houter = by * 2 + wn;            // 0..31
  const int hcol = houter * 16 + (lane & 15);
  const int rb = houter * 64 + (lane & 15);

  // ---- phase 0: x_proj with wih panel in LDS ----
  load_panel128(wih, bn, lWB, tid);
  __syncthreads();                           // panel loaded (vmcnt drained)
  floatx4 acc[4][4] = {};
  gemm_dbuf(xbf, lWB, lAb, acc, bm, lane, wm, wn, tid);

  const float b0 = biasp[rb], b1 = biasp[rb + 16], b2 = biasp[rb + 32],
              b3 = biasp[rb + 48];
  unsigned xprP[4][4][2];  // [mi][reg][pair] : (i,f) and (g,o) — 32 VGPRs
  float creg[4][4];        // 16 VGPRs
#pragma unroll
  for (int mi = 0; mi < 4; ++mi) {
    const int mrow0 = bm + wm * 64 + mi * 16 + (lane >> 4) * 4;
#pragma unroll
    for (int reg = 0; reg < 4; ++reg) {
      xprP[mi][reg][0] = pack_bf16(acc[mi][0][reg] + b0, acc[mi][1][reg] + b1);
      xprP[mi][reg][1] = pack_bf16(acc[mi][2][reg] + b2, acc[mi][3][reg] + b3);
      creg[mi][reg] = c0[(size_t)(mrow0 + reg) * KD + hcol];
    }
  }

  // ---- swap in the recurrent weights (one-time) ----
  load_panel128(whh, bn, lWB, tid);
  __syncthreads();                           // whh resident from here on

  // ---- 128 recurrent steps ----
#pragma unroll 1
  for (int t = 0; t < SEQLEN; ++t) {
    const short* hin = (t & 1) ? hB : hA;
    short* hout = (t & 1) ? hA : hB;

#pragma unroll
    for (int mi = 0; mi < 4; ++mi)
#pragma unroll
      for (int j = 0; j < 4; ++j)
        acc[mi][j] = floatx4{0.f, 0.f, 0.f, 0.f};

    gemm_dbuf(hin, lWB, lAb, acc, bm, lane, wm, wn, tid);

#pragma unroll
    for (int mi = 0; mi < 4; ++mi) {
      const int mrow0 = bm + wm * 64 + mi * 16 + (lane >> 4) * 4;
#pragma unroll
      for (int reg = 0; reg < 4; ++reg) {
        const int m = mrow0 + reg;
        float gi = acc[mi][0][reg] + unpack_lo(xprP[mi][reg][0]);
        float gf = acc[mi][1][reg] + unpack_hi(xprP[mi][reg][0]);
        float gg = acc[mi][2][reg] + unpack_lo(xprP[mi][reg][1]);
        float go = acc[mi][3][reg] + unpack_hi(xprP[mi][reg][1]);
        float si = fast_sig(gi);
        float sf = fast_sig(gf);
        float tg = fast_tanh(gg);
        float so = fast_sig(go);
        float cn = sf * creg[mi][reg] + si * tg;
        creg[mi][reg] = cn;
        float hn = so * fast_tanh(cn);
        const size_t ci = (size_t)m * KD + hcol;
        ((__hip_bfloat16*)hout)[ci] = __float2bfloat16(hn);
        if (t == SEQLEN - 1) {
          outH[ci] = hn;
          outC[ci] = cn;
        }
      }
    }
    if (t != SEQLEN - 1) group_barrier_xcd(gcnt, 16u * (unsigned)(t + 1));
  }
}

// =====================================================================
// Fallback path (round-1 proven, 2848 us): per-step kernels
// =====================================================================
__global__ __launch_bounds__(256, 2) void lstm_step(
    const short* __restrict__ hin, __hip_bfloat16* __restrict__ hout_bf,
    const short* __restrict__ W, const float* __restrict__ xp,
    float* __restrict__ c, float* __restrict__ hout_f32) {
  __shared__ __align__(16) short lA[128 * 64];
  __shared__ __align__(16) short lB[128 * 64];
  const int tid = threadIdx.x;
  const int lane = tid & 63;
  const int wid = tid >> 6;
  const int wm = wid >> 1, wn = wid & 1;
  const int bm = blockIdx.x * 128, bn = blockIdx.y * 128;

  floatx4 acc[4][4] = {};
  gemm_tile<128, 128, 256>(hin, W, acc, lA, lB, bm, bn, lane, wm, wn, tid);

  const int houter = blockIdx.y * 2 + wn;
  const int hcol = houter * 16 + (lane & 15);
  const int rb = houter * 64 + (lane & 15);
#pragma unroll
  for (int mi = 0; mi < 4; ++mi) {
    const int mrow0 = bm + wm * 64 + mi * 16 + (lane >> 4) * 4;
#pragma unroll
    for (int reg = 0; reg < 4; ++reg) {
      const int m = mrow0 + reg;
      const float* xpr = xp + (size_t)m * NG + rb;
      float si = fast_sig(acc[mi][0][reg] + xpr[0]);
      float sf = fast_sig(acc[mi][1][reg] + xpr[16]);
      float tg = fast_tanh(acc[mi][2][reg] + xpr[32]);
      float so = fast_sig(acc[mi][3][reg] + xpr[48]);
      const int ci = m * KD + hcol;
      float cn = sf * c[ci] + si * tg;
      c[ci] = cn;
      float hn = so * fast_tanh(cn);
      hout_bf[ci] = __float2bfloat16(hn);
      if (hout_f32) hout_f32[ci] = hn;
    }
  }
}

__global__ __launch_bounds__(256, 2) void xproj_gemm(
    const short* __restrict__ xbf, const short* __restrict__ Wih,
    const float* __restrict__ biasp, float* __restrict__ xp) {
  __shared__ __align__(16) short lA[128 * 64];
  __shared__ __align__(16) short lB[128 * 64];
  const int tid = threadIdx.x;
  const int lane = tid & 63;
  const int wid = tid >> 6;
  const int wm = wid >> 1, wn = wid & 1;
  const int bm = blockIdx.x * 128, bn = blockIdx.y * 128;

  floatx4 acc[4][4] = {};
  gemm_tile<128, 128, 256>(xbf, Wih, acc, lA, lB, bm, bn, lane, wm, wn, tid);

  const int houter = blockIdx.y * 2 + wn;
  const int rb = houter * 64 + (lane & 15);
  const float b0 = biasp[rb], b1 = biasp[rb + 16], b2 = biasp[rb + 32],
              b3 = biasp[rb + 48];
#pragma unroll
  for (int mi = 0; mi < 4; ++mi) {
    const int mrow0 = bm + wm * 64 + mi * 16 + (lane >> 4) * 4;
#pragma unroll
    for (int reg = 0; reg < 4; ++reg) {
      float* xpr = xp + (size_t)(mrow0 + reg) * NG + rb;
      xpr[0]  = acc[mi][0][reg] + b0;
      xpr[16] = acc[mi][1][reg] + b1;
      xpr[32] = acc[mi][2][reg] + b2;
      xpr[48] = acc[mi][3][reg] + b3;
    }
  }
}

// ---- prep kernels ----
__global__ void permw_k(const float* __restrict__ w,
                        __hip_bfloat16* __restrict__ o) {
  int idx = blockIdx.x * 256 + threadIdx.x;  // 2048*512
  int r = idx >> 9, k = idx & 511;
  int hout = r >> 6, g = (r >> 4) & 3, hin = r & 15;
  o[idx] = __float2bfloat16(w[(size_t)((g << 9) + hout * 16 + hin) * 512 + k]);
}

__global__ void bias_k(const float* __restrict__ bi, const float* __restrict__ bh,
                       float* __restrict__ o) {
  int r = blockIdx.x * 256 + threadIdx.x;  // 2048
  int hout = r >> 6, g = (r >> 4) & 3, hin = r & 15;
  int n = (g << 9) + hout * 16 + hin;
  o[r] = bi[n] + bh[n];
}

__global__ void f2bf_k(const float* __restrict__ in,
                       __hip_bfloat16* __restrict__ out, int n) {
  int i = blockIdx.x * 256 + threadIdx.x;
  if (i < n) out[i] = __float2bfloat16(in[i]);
}

extern "C" void kernel_launch(void* const* d_in, const int* in_sizes, int n_in,
                              void* d_out, int out_size, void* d_ws, size_t ws_size,
                              hipStream_t stream) {
  const float* start_emb = (const float*)d_in[0];
  const float* h0 = (const float*)d_in[1];
  const float* c0 = (const float*)d_in[2];
  const float* w_ih = (const float*)d_in[3];
  const float* w_hh = (const float*)d_in[4];
  const float* b_ih = (const float*)d_in[5];
  const float* b_hh = (const float*)d_in[6];
  // seq_length (d_in[7]) fixed at 128 by the reference setup.

  char* ws = (char*)d_ws;
  __hip_bfloat16* whh_p = (__hip_bfloat16*)(ws);                // 2 MB
  __hip_bfloat16* wih_p = (__hip_bfloat16*)(ws + (2ll << 20));  // 2 MB
  __hip_bfloat16* xbf   = (__hip_bfloat16*)(ws + (4ll << 20));  // 4 MB
  __hip_bfloat16* hbufA = (__hip_bfloat16*)(ws + (8ll << 20));  // 4 MB
  __hip_bfloat16* hbufB = (__hip_bfloat16*)(ws + (12ll << 20)); // 4 MB
  float* biasp          = (float*)(ws + (16ll << 20));          // 8 KB
  unsigned* sync_area   = (unsigned*)(ws + (16ll << 20) + 65536); // 8 KB
  float* xp             = (float*)(ws + (17ll << 20));          // 32 MB (fallback)

  float* outH = (float*)d_out;
  float* outC = (float*)d_out + (size_t)BATCH * KD;

  permw_k<<<4096, 256, 0, stream>>>(w_hh, whh_p);
  permw_k<<<4096, 256, 0, stream>>>(w_ih, wih_p);
  bias_k<<<8, 256, 0, stream>>>(b_ih, b_hh, biasp);
  f2bf_k<<<8192, 256, 0, stream>>>(start_emb, xbf, BATCH * KD);
  f2bf_k<<<8192, 256, 0, stream>>>(h0, hbufA, BATCH * KD);
  (void)hipMemsetAsync(sync_area, 0, 8192, stream);

  const short* a_xbf = (const short*)xbf;
  const short* a_wih = (const short*)wih_p;
  const short* a_whh = (const short*)whh_p;
  const float* a_bias = biasp;
  const float* a_c0 = c0;
  short* a_hA = (short*)hbufA;
  short* a_hB = (short*)hbufB;
  float* a_outH = outH;
  float* a_outC = outC;
  unsigned* a_sync = sync_area;
  void* args[] = {&a_xbf, &a_wih, &a_whh, &a_bias, &a_c0,
                  &a_hA, &a_hB, &a_outH, &a_outC, &a_sync};
  // 160 KiB dynamic LDS (panel 128K + 2x16K A dbuf) => 1 block/CU => 256
  // co-resident blocks = exactly 32 per XCD (G16: verified registration).
  hipError_t e = hipLaunchCooperativeKernel((const void*)lstm_persist,
                                            dim3(256), dim3(512), args,
                                            163840, stream);
  if (e != hipSuccess) {
    // deterministic fallback: proven round-1 per-step path
    (void)hipMemcpyAsync(outC, c0, (size_t)BATCH * KD * sizeof(float),
                         hipMemcpyDeviceToDevice, stream);
    dim3 grid(BATCH / 128, NG / 128);
    xproj_gemm<<<grid, 256, 0, stream>>>((const short*)xbf, (const short*)wih_p,
                                         biasp, xp);
    for (int t = 0; t < SEQLEN; ++t) {
      const short* hin = (const short*)((t & 1) ? hbufB : hbufA);
      __hip_bfloat16* hout = (t & 1) ? hbufA : hbufB;
      lstm_step<<<grid, 256, 0, stream>>>(hin, hout, (const short*)whh_p, xp,
                                          outC, (t == SEQLEN - 1) ? outH : nullptr);
    }
  }
}